// Round 1
// baseline (805.250 us; speedup 1.0000x reference)
//
#include <hip/hip_runtime.h>
#include <math.h>

// ---------------- helpers ----------------
__device__ __forceinline__ float wred_sum(float v) {
#pragma unroll
  for (int off = 32; off; off >>= 1) v += __shfl_xor(v, off, 64);
  return v;
}
__device__ __forceinline__ float wred_max(float v) {
#pragma unroll
  for (int off = 32; off; off >>= 1) v = fmaxf(v, __shfl_xor(v, off, 64));
  return v;
}
// monotonic float<->uint key for atomicMax on floats (handles negatives/-inf)
__device__ __forceinline__ unsigned f2key(float x) {
  unsigned b = __float_as_uint(x);
  return (b & 0x80000000u) ? ~b : (b | 0x80000000u);
}
__device__ __forceinline__ float key2f(unsigned k) {
  unsigned b = (k & 0x80000000u) ? (k & 0x7FFFFFFFu) : ~k;
  return __uint_as_float(b);
}

// ---------------- self-loop mean edge_attr + degree count ----------------
__global__ __launch_bounds__(256) void k_count_ea(const int* __restrict__ dst,
    const float* __restrict__ ea, int* __restrict__ cnt_i,
    float* __restrict__ sum_ea, int E) {
  int e = blockIdx.x * 256 + threadIdx.x;
  if (e >= E) return;
  int d = dst[e];
  atomicAdd(&cnt_i[d], 1);
  atomicAdd(&sum_ea[d], ea[e]);
}

__global__ __launch_bounds__(256) void k_mean(const int* __restrict__ cnt_i,
    const float* __restrict__ sum_ea, float* __restrict__ mean_ea, int N) {
  int n = blockIdx.x * 256 + threadIdx.x;
  if (n >= N) return;
  mean_ea[n] = sum_ea[n] / fmaxf((float)cnt_i[n], 1.0f);
}

// exclusive scan of (cnt+1) over N nodes -> row_start[N+1], cursor copy
__global__ __launch_bounds__(1024) void k_scan(const int* __restrict__ cnt_i,
    int* __restrict__ row_st, int* __restrict__ cursor, int N) {
  __shared__ int sums[1024];
  int tid = threadIdx.x;
  int per = (N + 1023) / 1024;
  int begin = tid * per, end = min(begin + per, N);
  int s = 0;
  for (int i = begin; i < end; ++i) s += cnt_i[i] + 1;
  sums[tid] = s;
  __syncthreads();
  for (int off = 1; off < 1024; off <<= 1) {
    int v = (tid >= off) ? sums[tid - off] : 0;
    __syncthreads();
    sums[tid] += v;
    __syncthreads();
  }
  int prefix = (tid == 0) ? 0 : sums[tid - 1];
  for (int i = begin; i < end; ++i) {
    row_st[i] = prefix;
    cursor[i] = prefix;
    prefix += cnt_i[i] + 1;
  }
  if (tid == 0) row_st[N] = sums[1023];
}

// scatter edge ids (incl. self loops e=E+n) into CSR perm
__global__ __launch_bounds__(256) void k_scatter(const int* __restrict__ dst,
    int* __restrict__ cursor, int* __restrict__ perm, int E, int E2) {
  int e = blockIdx.x * 256 + threadIdx.x;
  if (e >= E2) return;
  int d = (e < E) ? dst[e] : (e - E);
  int pos = atomicAdd(&cursor[d], 1);
  perm[pos] = e;
}

// ---------------- f32 GEMM: C[M,Nc] = A[M,K] * W[Nc,K]^T + bias ----------------
#define BM 64
#define BN 64
#define BKK 32
__global__ __launch_bounds__(256) void k_gemm_nt(const float* __restrict__ A,
    const float* __restrict__ W, const float* __restrict__ bias,
    float* __restrict__ C, int M, int Nc, int K) {
  __shared__ float As[BKK][BM + 4];
  __shared__ float Ws[BKK][BN + 4];
  int m0 = blockIdx.x * BM, n0 = blockIdx.y * BN;
  int tid = threadIdx.x;
  int tx = tid & 15, ty = tid >> 4;
  float acc[4][4] = {};
  for (int k0 = 0; k0 < K; k0 += BKK) {
    for (int idx = tid; idx < BM * BKK; idx += 256) {
      int m = idx >> 5, k = idx & 31;
      int gm = m0 + m;
      As[k][m] = (gm < M) ? A[(size_t)gm * K + k0 + k] : 0.f;
    }
    for (int idx = tid; idx < BN * BKK; idx += 256) {
      int n = idx >> 5, k = idx & 31;
      Ws[k][n] = W[(size_t)(n0 + n) * K + k0 + k];
    }
    __syncthreads();
#pragma unroll
    for (int k = 0; k < BKK; ++k) {
      float4 a4 = *(const float4*)&As[k][ty * 4];
      float4 w4 = *(const float4*)&Ws[k][tx * 4];
      float av[4] = {a4.x, a4.y, a4.z, a4.w};
      float wv[4] = {w4.x, w4.y, w4.z, w4.w};
#pragma unroll
      for (int i = 0; i < 4; ++i)
#pragma unroll
        for (int j = 0; j < 4; ++j) acc[i][j] += av[i] * wv[j];
    }
    __syncthreads();
  }
#pragma unroll
  for (int i = 0; i < 4; ++i) {
    int gm = m0 + ty * 4 + i;
    if (gm >= M) continue;
#pragma unroll
    for (int j = 0; j < 4; ++j) {
      int gn = n0 + tx * 4 + j;
      C[(size_t)gm * Nc + gn] = acc[i][j] + bias[gn];
    }
  }
}

// ---------------- layer 1 (H=4, C=64) edge scores ----------------
__global__ __launch_bounds__(256) void k_scores1(const float* __restrict__ xl,
    const float* __restrict__ xr, const int* __restrict__ src,
    const int* __restrict__ dst, const float* __restrict__ ea,
    const float* __restrict__ mean_ea, const float* __restrict__ We,
    const float* __restrict__ att, float* __restrict__ s_out, int E, int E2) {
  int eid = blockIdx.x * 4 + (threadIdx.x >> 6);
  int lane = threadIdx.x & 63;
  if (eid >= E2) return;
  int sn, dn; float av;
  if (eid < E) { sn = src[eid]; dn = dst[eid]; av = ea[eid]; }
  else { sn = dn = eid - E; av = mean_ea[sn]; }
  const float* xls = xl + (size_t)sn * 256;
  const float* xrd = xr + (size_t)dn * 256;
  float t[4];
#pragma unroll
  for (int h = 0; h < 4; ++h) {
    int j = h * 64 + lane;
    float v = xls[j] + xrd[j] + av * We[j];
    v = v > 0.f ? v : 0.2f * v;
    t[h] = att[j] * v;
  }
#pragma unroll
  for (int off = 32; off; off >>= 1)
#pragma unroll
    for (int h = 0; h < 4; ++h) t[h] += __shfl_xor(t[h], off, 64);
  if (lane == 0) {
#pragma unroll
    for (int h = 0; h < 4; ++h) s_out[(size_t)eid * 4 + h] = t[h];
  }
}

// ---------------- layer 1 per-node softmax + aggregation ----------------
__global__ __launch_bounds__(256) void k_agg1(const float* __restrict__ xl,
    const float* __restrict__ s1, const int* __restrict__ perm,
    const int* __restrict__ row_st, const int* __restrict__ src,
    const float* __restrict__ bias, float* __restrict__ out, int E, int N) {
  int n = blockIdx.x * 4 + (threadIdx.x >> 6);
  int lane = threadIdx.x & 63;
  if (n >= N) return;
  int a = row_st[n], b = row_st[n + 1];
  float m[4] = {-INFINITY, -INFINITY, -INFINITY, -INFINITY};
  for (int i = a + lane; i < b; i += 64) {
    int e = perm[i];
#pragma unroll
    for (int h = 0; h < 4; ++h) m[h] = fmaxf(m[h], s1[(size_t)e * 4 + h]);
  }
#pragma unroll
  for (int off = 32; off; off >>= 1)
#pragma unroll
    for (int h = 0; h < 4; ++h) m[h] = fmaxf(m[h], __shfl_xor(m[h], off, 64));
  float den[4] = {0, 0, 0, 0};
  for (int i = a + lane; i < b; i += 64) {
    int e = perm[i];
#pragma unroll
    for (int h = 0; h < 4; ++h) den[h] += __expf(s1[(size_t)e * 4 + h] - m[h]);
  }
#pragma unroll
  for (int off = 32; off; off >>= 1)
#pragma unroll
    for (int h = 0; h < 4; ++h) den[h] += __shfl_xor(den[h], off, 64);
  float inv[4];
#pragma unroll
  for (int h = 0; h < 4; ++h) inv[h] = 1.f / (den[h] + 1e-16f);
  float acc[4] = {0, 0, 0, 0};
  for (int i = a; i < b; ++i) {
    int e = perm[i];
    int sn = (e < E) ? src[e] : n;
    const float* xs = xl + (size_t)sn * 256;
#pragma unroll
    for (int h = 0; h < 4; ++h) {
      float ex = __expf(s1[(size_t)e * 4 + h] - m[h]);
      acc[h] += ex * xs[h * 64 + lane];
    }
  }
#pragma unroll
  for (int h = 0; h < 4; ++h) {
    float v = acc[h] * inv[h] + bias[h * 64 + lane];
    out[(size_t)n * 256 + h * 64 + lane] = v > 0.f ? v : 0.f;
  }
}

// ---------------- layer 2 (H=1, C=64) ----------------
__global__ __launch_bounds__(256) void k_scores2(const float* __restrict__ xl,
    const float* __restrict__ xr, const int* __restrict__ src,
    const int* __restrict__ dst, const float* __restrict__ ea,
    const float* __restrict__ mean_ea, const float* __restrict__ We,
    const float* __restrict__ att, float* __restrict__ s_out, int E, int E2) {
  int eid = blockIdx.x * 4 + (threadIdx.x >> 6);
  int lane = threadIdx.x & 63;
  if (eid >= E2) return;
  int sn, dn; float av;
  if (eid < E) { sn = src[eid]; dn = dst[eid]; av = ea[eid]; }
  else { sn = dn = eid - E; av = mean_ea[sn]; }
  float v = xl[(size_t)sn * 64 + lane] + xr[(size_t)dn * 64 + lane] + av * We[lane];
  v = v > 0.f ? v : 0.2f * v;
  float t = att[lane] * v;
  t = wred_sum(t);
  if (lane == 0) s_out[eid] = t;
}

__global__ __launch_bounds__(256) void k_agg2(const float* __restrict__ xl,
    const float* __restrict__ s2, const int* __restrict__ perm,
    const int* __restrict__ row_st, const int* __restrict__ src,
    const float* __restrict__ bias, float* __restrict__ out, int E, int N) {
  int n = blockIdx.x * 4 + (threadIdx.x >> 6);
  int lane = threadIdx.x & 63;
  if (n >= N) return;
  int a = row_st[n], b = row_st[n + 1];
  float m = -INFINITY;
  for (int i = a + lane; i < b; i += 64) m = fmaxf(m, s2[perm[i]]);
  m = wred_max(m);
  float den = 0;
  for (int i = a + lane; i < b; i += 64) den += __expf(s2[perm[i]] - m);
  den = wred_sum(den);
  float inv = 1.f / (den + 1e-16f);
  float acc = 0;
  for (int i = a; i < b; ++i) {
    int e = perm[i];
    int sn = (e < E) ? src[e] : n;
    acc += __expf(s2[e] - m) * xl[(size_t)sn * 64 + lane];
  }
  float v = acc * inv + bias[lane];
  out[(size_t)n * 64 + lane] = v > 0.f ? v : 0.f;
}

// ---------------- global mean pool ----------------
__global__ __launch_bounds__(256) void k_pool(const float* __restrict__ h2,
    float* __restrict__ g_sum, int N) {
  __shared__ float red[4][64];
  int b = blockIdx.x, tid = threadIdx.x;
  int lane = tid & 63, w = tid >> 6;
  int rows_per = (N + gridDim.x - 1) / gridDim.x;
  int r0 = b * rows_per, r1 = min(r0 + rows_per, N);
  float s = 0;
  for (int r = r0 + w; r < r1; r += 4) s += h2[(size_t)r * 64 + lane];
  red[w][lane] = s;
  __syncthreads();
  if (w == 0) {
    float v = red[0][lane] + red[1][lane] + red[2][lane] + red[3][lane];
    atomicAdd(&g_sum[lane], v);
  }
}

// mean -> g, state potential, sigmoid(alpha)
__global__ void k_head(const float* __restrict__ g_sum, const float* __restrict__ Wp,
    const float* __restrict__ bp, const float* __restrict__ alpha,
    float* __restrict__ g, float* __restrict__ out, int N, int NA) {
  int lane = threadIdx.x;
  float gv = g_sum[lane] / (float)N;
  g[lane] = gv;
  float t = wred_sum(gv * Wp[lane]);
  if (lane == 0) {
    float sp = t + bp[0];
    out[NA] = sp > 0.f ? sp : 0.f;
    out[NA + 1] = 1.f / (1.f + __expf(-alpha[0]));
  }
}

__global__ void k_aflag(const int* __restrict__ actions, unsigned char* __restrict__ aflag,
                        int n_act) {
  int i = threadIdx.x;
  if (i < n_act) aflag[actions[i]] = 1;
}

// ---------------- masked logits + softmax (3 passes) ----------------
__global__ __launch_bounds__(256) void k_logits(const float* __restrict__ g,
    const float* __restrict__ Wf, const float* __restrict__ bf,
    const unsigned char* __restrict__ aflag, const int* __restrict__ src,
    const int* __restrict__ dst, float* __restrict__ logits,
    unsigned* __restrict__ gmax_key, int E, int NA) {
  __shared__ float gs[64];
  int tid = threadIdx.x;
  if (tid < 64) gs[tid] = g[tid];
  __syncthreads();
  int i = blockIdx.x * 256 + tid;
  float val = -INFINITY;
  if (i < NA) {
    bool keep = (!aflag[i]) && (i >= E || src[i] != dst[i]);
    if (keep) {
      const float4* w4 = (const float4*)(Wf + (size_t)i * 64);
      float acc = 0.f;
#pragma unroll
      for (int j = 0; j < 16; ++j) {
        float4 w = w4[j];
        acc += w.x * gs[4 * j] + w.y * gs[4 * j + 1] + w.z * gs[4 * j + 2] + w.w * gs[4 * j + 3];
      }
      val = acc + bf[i];
    }
    logits[i] = val;
  }
  float mv = wred_max(val);
  if ((tid & 63) == 0) atomicMax(gmax_key, f2key(mv));
}

__global__ __launch_bounds__(256) void k_exp(float* __restrict__ logits,
    const unsigned* __restrict__ gmax_key, float* __restrict__ gsum, int NA) {
  int i = blockIdx.x * 256 + threadIdx.x;
  float gmax = key2f(*gmax_key);
  float ex = 0.f;
  if (i < NA) {
    float v = logits[i];
    ex = (v == -INFINITY) ? 0.f : __expf(v - gmax);
    logits[i] = ex;
  }
  float s = wred_sum(ex);
  if ((threadIdx.x & 63) == 0) atomicAdd(gsum, s);
}

__global__ __launch_bounds__(256) void k_norm(const float* __restrict__ logits,
    const float* __restrict__ gsum, float* __restrict__ out, int NA) {
  int i = blockIdx.x * 256 + threadIdx.x;
  if (i < NA) out[i] = logits[i] / (*gsum);
}

// ---------------- launch ----------------
extern "C" void kernel_launch(void* const* d_in, const int* in_sizes, int n_in,
                              void* d_out, int out_size, void* d_ws, size_t ws_size,
                              hipStream_t stream) {
  const float* x      = (const float*)d_in[0];
  const int*   eidx   = (const int*)d_in[1];
  const float* eattr  = (const float*)d_in[2];
  const int*   actions= (const int*)d_in[3];
  const float* Wl1 = (const float*)d_in[4];
  const float* bl1 = (const float*)d_in[5];
  const float* Wr1 = (const float*)d_in[6];
  const float* br1 = (const float*)d_in[7];
  const float* We1 = (const float*)d_in[8];
  const float* att1= (const float*)d_in[9];
  const float* bias1=(const float*)d_in[10];
  const float* Wl2 = (const float*)d_in[11];
  const float* bl2 = (const float*)d_in[12];
  const float* Wr2 = (const float*)d_in[13];
  const float* br2 = (const float*)d_in[14];
  const float* We2 = (const float*)d_in[15];
  const float* att2= (const float*)d_in[16];
  const float* bias2=(const float*)d_in[17];
  const float* Wf  = (const float*)d_in[18];
  const float* bf  = (const float*)d_in[19];
  const float* Wp  = (const float*)d_in[20];
  const float* bp  = (const float*)d_in[21];
  const float* alpha=(const float*)d_in[22];

  const int F = 128;
  const int N = in_sizes[0] / F;       // 20000
  const int E = in_sizes[2];           // 400000
  const int E2 = E + N;
  const int NA = E + 1;
  const int n_act = in_sizes[3];
  const int* src = eidx;
  const int* dst = eidx + E;

  float* ws = (float*)d_ws;
  size_t p = 0;
  int*      cnt_i    = (int*)(ws + p);      p += (size_t)N;
  float*    sum_ea   = ws + p;              p += (size_t)N;
  float*    g_sum    = ws + p;              p += 64;
  unsigned* gmax_key = (unsigned*)(ws + p); p += 64;
  float*    gsum     = ws + p;              p += 64;
  size_t zero_bytes = p * sizeof(float);
  float*    g        = ws + p;              p += 64;
  float*    mean_ea  = ws + p;              p += (size_t)N;
  int*      row_st   = (int*)(ws + p);      p += (size_t)N + 64;
  int*      cursor   = (int*)(ws + p);      p += (size_t)N;
  int*      perm     = (int*)(ws + p);      p += (size_t)E2;
  float*    s1       = ws + p;              p += (size_t)E2 * 4;
  float*    s2       = ws + p;              p += (size_t)E2;
  float*    logits   = ws + p;              p += (size_t)NA + 64;
  float*    regA     = ws + p;              p += (size_t)N * 256;
  float*    regB     = ws + p;              p += (size_t)N * 256;
  unsigned char* aflag = (unsigned char*)(ws + p);

  float* out = (float*)d_out;

  hipMemsetAsync(d_ws, 0, zero_bytes, stream);
  hipMemsetAsync(aflag, 0, (size_t)NA, stream);

  // CSR build + self-loop edge attr
  k_count_ea<<<(E + 255) / 256, 256, 0, stream>>>(dst, eattr, cnt_i, sum_ea, E);
  k_mean<<<(N + 255) / 256, 256, 0, stream>>>(cnt_i, sum_ea, mean_ea, N);
  k_scan<<<1, 1024, 0, stream>>>(cnt_i, row_st, cursor, N);
  k_scatter<<<(E2 + 255) / 256, 256, 0, stream>>>(dst, cursor, perm, E, E2);

  // layer 1 projections: xl1=regA, xr1=regB
  dim3 g1((N + 63) / 64, 4);
  k_gemm_nt<<<g1, 256, 0, stream>>>(x, Wl1, bl1, regA, N, 256, F);
  k_gemm_nt<<<g1, 256, 0, stream>>>(x, Wr1, br1, regB, N, 256, F);
  k_scores1<<<(E2 + 3) / 4, 256, 0, stream>>>(regA, regB, src, dst, eattr, mean_ea,
                                              We1, att1, s1, E, E2);
  // h1 overwrites xr1 (regB): agg reads only xl1(regA) + s1
  k_agg1<<<(N + 3) / 4, 256, 0, stream>>>(regA, s1, perm, row_st, src, bias1, regB, E, N);

  // layer 2 projections from h1(regB): xl2 = regA, xr2 = regA + N*64
  float* xl2 = regA;
  float* xr2 = regA + (size_t)N * 64;
  float* h2  = regA + (size_t)N * 128;
  dim3 g2((N + 63) / 64, 1);
  k_gemm_nt<<<g2, 256, 0, stream>>>(regB, Wl2, bl2, xl2, N, 64, 256);
  k_gemm_nt<<<g2, 256, 0, stream>>>(regB, Wr2, br2, xr2, N, 64, 256);
  k_scores2<<<(E2 + 3) / 4, 256, 0, stream>>>(xl2, xr2, src, dst, eattr, mean_ea,
                                              We2, att2, s2, E, E2);
  k_agg2<<<(N + 3) / 4, 256, 0, stream>>>(xl2, s2, perm, row_st, src, bias2, h2, E, N);

  // head
  k_pool<<<128, 256, 0, stream>>>(h2, g_sum, N);
  k_head<<<1, 64, 0, stream>>>(g_sum, Wp, bp, alpha, g, out, N, NA);
  k_aflag<<<1, 128, 0, stream>>>(actions, aflag, n_act);
  int nb = (NA + 255) / 256;
  k_logits<<<nb, 256, 0, stream>>>(g, Wf, bf, aflag, src, dst, logits, gmax_key, E, NA);
  k_exp<<<nb, 256, 0, stream>>>(logits, gmax_key, gsum, NA);
  k_norm<<<nb, 256, 0, stream>>>(logits, gsum, out, NA);
}

// Round 2
// 615.177 us; speedup vs baseline: 1.3090x; 1.3090x over previous
//
#include <hip/hip_runtime.h>
#include <math.h>

// ---------------- helpers ----------------
__device__ __forceinline__ float wred_sum(float v) {
#pragma unroll
  for (int off = 32; off; off >>= 1) v += __shfl_xor(v, off, 64);
  return v;
}
__device__ __forceinline__ float wred_max(float v) {
#pragma unroll
  for (int off = 32; off; off >>= 1) v = fmaxf(v, __shfl_xor(v, off, 64));
  return v;
}
// monotonic float<->uint key for atomicMax on floats (handles negatives/-inf)
__device__ __forceinline__ unsigned f2key(float x) {
  unsigned b = __float_as_uint(x);
  return (b & 0x80000000u) ? ~b : (b | 0x80000000u);
}
__device__ __forceinline__ float key2f(unsigned k) {
  unsigned b = (k & 0x80000000u) ? (k & 0x7FFFFFFFu) : ~k;
  return __uint_as_float(b);
}

// ---------------- self-loop mean edge_attr + degree count ----------------
__global__ __launch_bounds__(256) void k_count_ea(const int* __restrict__ dst,
    const float* __restrict__ ea, int* __restrict__ cnt_i,
    float* __restrict__ sum_ea, int E) {
  int e = blockIdx.x * 256 + threadIdx.x;
  if (e >= E) return;
  int d = dst[e];
  atomicAdd(&cnt_i[d], 1);
  atomicAdd(&sum_ea[d], ea[e]);
}

__global__ __launch_bounds__(256) void k_mean(const int* __restrict__ cnt_i,
    const float* __restrict__ sum_ea, float* __restrict__ mean_ea, int N) {
  int n = blockIdx.x * 256 + threadIdx.x;
  if (n >= N) return;
  mean_ea[n] = sum_ea[n] / fmaxf((float)cnt_i[n], 1.0f);
}

// exclusive scan of (cnt+1) over N nodes -> row_start[N+1], cursor copy
__global__ __launch_bounds__(1024) void k_scan(const int* __restrict__ cnt_i,
    int* __restrict__ row_st, int* __restrict__ cursor, int N) {
  __shared__ int sums[1024];
  int tid = threadIdx.x;
  int per = (N + 1023) / 1024;
  int begin = tid * per, end = min(begin + per, N);
  int s = 0;
  for (int i = begin; i < end; ++i) s += cnt_i[i] + 1;
  sums[tid] = s;
  __syncthreads();
  for (int off = 1; off < 1024; off <<= 1) {
    int v = (tid >= off) ? sums[tid - off] : 0;
    __syncthreads();
    sums[tid] += v;
    __syncthreads();
  }
  int prefix = (tid == 0) ? 0 : sums[tid - 1];
  for (int i = begin; i < end; ++i) {
    row_st[i] = prefix;
    cursor[i] = prefix;
    prefix += cnt_i[i] + 1;
  }
  if (tid == 0) row_st[N] = sums[1023];
}

// scatter edge ids (incl. self loops e=E+n) into CSR perm
__global__ __launch_bounds__(256) void k_scatter(const int* __restrict__ dst,
    int* __restrict__ cursor, int* __restrict__ perm, int E, int E2) {
  int e = blockIdx.x * 256 + threadIdx.x;
  if (e >= E2) return;
  int d = (e < E) ? dst[e] : (e - E);
  int pos = atomicAdd(&cursor[d], 1);
  perm[pos] = e;
}

// ---------------- f32 GEMM: C[M,Nc] = A[M,K] * W[Nc,K]^T + bias ----------------
#define BM 64
#define BN 64
#define BKK 32
__global__ __launch_bounds__(256) void k_gemm_nt(const float* __restrict__ A,
    const float* __restrict__ W, const float* __restrict__ bias,
    float* __restrict__ C, int M, int Nc, int K) {
  __shared__ float As[BKK][BM + 4];
  __shared__ float Ws[BKK][BN + 4];
  int m0 = blockIdx.x * BM, n0 = blockIdx.y * BN;
  int tid = threadIdx.x;
  int tx = tid & 15, ty = tid >> 4;
  float acc[4][4] = {};
  for (int k0 = 0; k0 < K; k0 += BKK) {
    for (int idx = tid; idx < BM * BKK; idx += 256) {
      int m = idx >> 5, k = idx & 31;
      int gm = m0 + m;
      As[k][m] = (gm < M) ? A[(size_t)gm * K + k0 + k] : 0.f;
    }
    for (int idx = tid; idx < BN * BKK; idx += 256) {
      int n = idx >> 5, k = idx & 31;
      Ws[k][n] = W[(size_t)(n0 + n) * K + k0 + k];
    }
    __syncthreads();
#pragma unroll
    for (int k = 0; k < BKK; ++k) {
      float4 a4 = *(const float4*)&As[k][ty * 4];
      float4 w4 = *(const float4*)&Ws[k][tx * 4];
      float av[4] = {a4.x, a4.y, a4.z, a4.w};
      float wv[4] = {w4.x, w4.y, w4.z, w4.w};
#pragma unroll
      for (int i = 0; i < 4; ++i)
#pragma unroll
        for (int j = 0; j < 4; ++j) acc[i][j] += av[i] * wv[j];
    }
    __syncthreads();
  }
#pragma unroll
  for (int i = 0; i < 4; ++i) {
    int gm = m0 + ty * 4 + i;
    if (gm >= M) continue;
#pragma unroll
    for (int j = 0; j < 4; ++j) {
      int gn = n0 + tx * 4 + j;
      C[(size_t)gm * Nc + gn] = acc[i][j] + bias[gn];
    }
  }
}

// ---------------- layer 1 fused: scores + online softmax + aggregation ----------------
// one wave per node; lane holds channels 4*lane..4*lane+3 (head = lane>>4)
__global__ __launch_bounds__(256) void k_fused1(const float* __restrict__ xl,
    const float* __restrict__ xr, const int* __restrict__ src,
    const float* __restrict__ ea, const float* __restrict__ mean_ea,
    const int* __restrict__ perm, const int* __restrict__ row_st,
    const float* __restrict__ We, const float* __restrict__ att,
    const float* __restrict__ bias, float* __restrict__ out, int E, int N) {
  int n = blockIdx.x * 4 + (threadIdx.x >> 6);
  int lane = threadIdx.x & 63;
  if (n >= N) return;
  const float4 We4 = ((const float4*)We)[lane];
  const float4 at4 = ((const float4*)att)[lane];
  const float4 xr4 = *(const float4*)(xr + (size_t)n * 256 + lane * 4);
  int a = row_st[n], b = row_st[n + 1];
  float m = -INFINITY, den = 0.f;
  float ax = 0.f, ay = 0.f, az = 0.f, aw = 0.f;
  int e0 = perm[a];
  int sn_nx = (e0 < E) ? src[e0] : n;
  float av_nx = (e0 < E) ? ea[e0] : mean_ea[n];
  for (int i = a; i < b; ++i) {
    int sn = sn_nx;
    float av = av_nx;
    const float4 xv = *(const float4*)(xl + (size_t)sn * 256 + lane * 4);
    if (i + 1 < b) {
      int e2 = perm[i + 1];
      sn_nx = (e2 < E) ? src[e2] : n;
      av_nx = (e2 < E) ? ea[e2] : mean_ea[n];
    }
    float vx = xv.x + xr4.x + av * We4.x; vx = vx > 0.f ? vx : 0.2f * vx;
    float vy = xv.y + xr4.y + av * We4.y; vy = vy > 0.f ? vy : 0.2f * vy;
    float vz = xv.z + xr4.z + av * We4.z; vz = vz > 0.f ? vz : 0.2f * vz;
    float vw = xv.w + xr4.w + av * We4.w; vw = vw > 0.f ? vw : 0.2f * vw;
    float t = at4.x * vx + at4.y * vy + at4.z * vz + at4.w * vw;
    // reduce within 16-lane head group
    t += __shfl_xor(t, 1, 16);
    t += __shfl_xor(t, 2, 16);
    t += __shfl_xor(t, 4, 16);
    t += __shfl_xor(t, 8, 16);
    if (t > m) {
      float sc = __expf(m - t);
      m = t;
      den *= sc; ax *= sc; ay *= sc; az *= sc; aw *= sc;
    }
    float ex = __expf(t - m);
    den += ex;
    ax += ex * xv.x; ay += ex * xv.y; az += ex * xv.z; aw += ex * xv.w;
  }
  float inv = 1.f / (den + 1e-16f);
  const float4 b4 = ((const float4*)bias)[lane];
  float4 o;
  o.x = fmaxf(ax * inv + b4.x, 0.f);
  o.y = fmaxf(ay * inv + b4.y, 0.f);
  o.z = fmaxf(az * inv + b4.z, 0.f);
  o.w = fmaxf(aw * inv + b4.w, 0.f);
  *(float4*)(out + (size_t)n * 256 + lane * 4) = o;
}

// ---------------- layer 2 fused (H=1, C=64) ----------------
__global__ __launch_bounds__(256) void k_fused2(const float* __restrict__ xl,
    const float* __restrict__ xr, const int* __restrict__ src,
    const float* __restrict__ ea, const float* __restrict__ mean_ea,
    const int* __restrict__ perm, const int* __restrict__ row_st,
    const float* __restrict__ We, const float* __restrict__ att,
    const float* __restrict__ bias, float* __restrict__ out, int E, int N) {
  int n = blockIdx.x * 4 + (threadIdx.x >> 6);
  int lane = threadIdx.x & 63;
  if (n >= N) return;
  const float Wev = We[lane];
  const float atv = att[lane];
  const float xrv = xr[(size_t)n * 64 + lane];
  int a = row_st[n], b = row_st[n + 1];
  float m = -INFINITY, den = 0.f, acc = 0.f;
  int e0 = perm[a];
  int sn_nx = (e0 < E) ? src[e0] : n;
  float av_nx = (e0 < E) ? ea[e0] : mean_ea[n];
  for (int i = a; i < b; ++i) {
    int sn = sn_nx;
    float av = av_nx;
    float xv = xl[(size_t)sn * 64 + lane];
    if (i + 1 < b) {
      int e2 = perm[i + 1];
      sn_nx = (e2 < E) ? src[e2] : n;
      av_nx = (e2 < E) ? ea[e2] : mean_ea[n];
    }
    float v = xv + xrv + av * Wev;
    v = v > 0.f ? v : 0.2f * v;
    float t = wred_sum(atv * v);
    if (t > m) {
      float sc = __expf(m - t);
      m = t; den *= sc; acc *= sc;
    }
    float ex = __expf(t - m);
    den += ex;
    acc += ex * xv;
  }
  float v = acc / (den + 1e-16f) + bias[lane];
  out[(size_t)n * 64 + lane] = v > 0.f ? v : 0.f;
}

// ---------------- global mean pool ----------------
__global__ __launch_bounds__(256) void k_pool(const float* __restrict__ h2,
    float* __restrict__ g_sum, int N) {
  __shared__ float red[4][64];
  int b = blockIdx.x, tid = threadIdx.x;
  int lane = tid & 63, w = tid >> 6;
  int rows_per = (N + gridDim.x - 1) / gridDim.x;
  int r0 = b * rows_per, r1 = min(r0 + rows_per, N);
  float s = 0;
  for (int r = r0 + w; r < r1; r += 4) s += h2[(size_t)r * 64 + lane];
  red[w][lane] = s;
  __syncthreads();
  if (w == 0) {
    float v = red[0][lane] + red[1][lane] + red[2][lane] + red[3][lane];
    atomicAdd(&g_sum[lane], v);
  }
}

// mean -> g, state potential, sigmoid(alpha)
__global__ void k_head(const float* __restrict__ g_sum, const float* __restrict__ Wp,
    const float* __restrict__ bp, const float* __restrict__ alpha,
    float* __restrict__ g, float* __restrict__ out, int N, int NA) {
  int lane = threadIdx.x;
  float gv = g_sum[lane] / (float)N;
  g[lane] = gv;
  float t = wred_sum(gv * Wp[lane]);
  if (lane == 0) {
    float sp = t + bp[0];
    out[NA] = sp > 0.f ? sp : 0.f;
    out[NA + 1] = 1.f / (1.f + __expf(-alpha[0]));
  }
}

__global__ void k_aflag(const int* __restrict__ actions, unsigned char* __restrict__ aflag,
                        int n_act) {
  int i = threadIdx.x;
  if (i < n_act) aflag[actions[i]] = 1;
}

// ---------------- masked logits + softmax (3 passes) ----------------
__global__ __launch_bounds__(256) void k_logits(const float* __restrict__ g,
    const float* __restrict__ Wf, const float* __restrict__ bf,
    const unsigned char* __restrict__ aflag, const int* __restrict__ src,
    const int* __restrict__ dst, float* __restrict__ logits,
    unsigned* __restrict__ gmax_key, int E, int NA) {
  __shared__ float gs[64];
  int tid = threadIdx.x;
  if (tid < 64) gs[tid] = g[tid];
  __syncthreads();
  int i = blockIdx.x * 256 + tid;
  float val = -INFINITY;
  if (i < NA) {
    bool keep = (!aflag[i]) && (i >= E || src[i] != dst[i]);
    if (keep) {
      const float4* w4 = (const float4*)(Wf + (size_t)i * 64);
      float acc = 0.f;
#pragma unroll
      for (int j = 0; j < 16; ++j) {
        float4 w = w4[j];
        acc += w.x * gs[4 * j] + w.y * gs[4 * j + 1] + w.z * gs[4 * j + 2] + w.w * gs[4 * j + 3];
      }
      val = acc + bf[i];
    }
    logits[i] = val;
  }
  float mv = wred_max(val);
  if ((tid & 63) == 0) atomicMax(gmax_key, f2key(mv));
}

__global__ __launch_bounds__(256) void k_exp(float* __restrict__ logits,
    const unsigned* __restrict__ gmax_key, float* __restrict__ gsum, int NA) {
  int i = blockIdx.x * 256 + threadIdx.x;
  float gmax = key2f(*gmax_key);
  float ex = 0.f;
  if (i < NA) {
    float v = logits[i];
    ex = (v == -INFINITY) ? 0.f : __expf(v - gmax);
    logits[i] = ex;
  }
  float s = wred_sum(ex);
  if ((threadIdx.x & 63) == 0) atomicAdd(gsum, s);
}

__global__ __launch_bounds__(256) void k_norm(const float* __restrict__ logits,
    const float* __restrict__ gsum, float* __restrict__ out, int NA) {
  int i = blockIdx.x * 256 + threadIdx.x;
  if (i < NA) out[i] = logits[i] / (*gsum);
}

// ---------------- launch ----------------
extern "C" void kernel_launch(void* const* d_in, const int* in_sizes, int n_in,
                              void* d_out, int out_size, void* d_ws, size_t ws_size,
                              hipStream_t stream) {
  const float* x      = (const float*)d_in[0];
  const int*   eidx   = (const int*)d_in[1];
  const float* eattr  = (const float*)d_in[2];
  const int*   actions= (const int*)d_in[3];
  const float* Wl1 = (const float*)d_in[4];
  const float* bl1 = (const float*)d_in[5];
  const float* Wr1 = (const float*)d_in[6];
  const float* br1 = (const float*)d_in[7];
  const float* We1 = (const float*)d_in[8];
  const float* att1= (const float*)d_in[9];
  const float* bias1=(const float*)d_in[10];
  const float* Wl2 = (const float*)d_in[11];
  const float* bl2 = (const float*)d_in[12];
  const float* Wr2 = (const float*)d_in[13];
  const float* br2 = (const float*)d_in[14];
  const float* We2 = (const float*)d_in[15];
  const float* att2= (const float*)d_in[16];
  const float* bias2=(const float*)d_in[17];
  const float* Wf  = (const float*)d_in[18];
  const float* bf  = (const float*)d_in[19];
  const float* Wp  = (const float*)d_in[20];
  const float* bp  = (const float*)d_in[21];
  const float* alpha=(const float*)d_in[22];

  const int F = 128;
  const int N = in_sizes[0] / F;       // 20000
  const int E = in_sizes[2];           // 400000
  const int E2 = E + N;
  const int NA = E + 1;
  const int n_act = in_sizes[3];
  const int* src = eidx;
  const int* dst = eidx + E;

  float* ws = (float*)d_ws;
  size_t p = 0;
  int*      cnt_i    = (int*)(ws + p);      p += (size_t)N;
  float*    sum_ea   = ws + p;              p += (size_t)N;
  float*    g_sum    = ws + p;              p += 64;
  unsigned* gmax_key = (unsigned*)(ws + p); p += 64;
  float*    gsum     = ws + p;              p += 64;
  size_t zero_bytes = p * sizeof(float);
  float*    g        = ws + p;              p += 64;
  float*    mean_ea  = ws + p;              p += (size_t)N;
  int*      row_st   = (int*)(ws + p);      p += (size_t)N + 64;
  int*      cursor   = (int*)(ws + p);      p += (size_t)N;
  int*      perm     = (int*)(ws + p);      p += (size_t)E2;
  float*    logits   = ws + p;              p += (size_t)NA + 64;
  float*    regA     = ws + p;              p += (size_t)N * 256;
  float*    regB     = ws + p;              p += (size_t)N * 256;
  unsigned char* aflag = (unsigned char*)(ws + p);

  float* out = (float*)d_out;

  hipMemsetAsync(d_ws, 0, zero_bytes, stream);
  hipMemsetAsync(aflag, 0, (size_t)NA, stream);

  // CSR build + self-loop edge attr
  k_count_ea<<<(E + 255) / 256, 256, 0, stream>>>(dst, eattr, cnt_i, sum_ea, E);
  k_mean<<<(N + 255) / 256, 256, 0, stream>>>(cnt_i, sum_ea, mean_ea, N);
  k_scan<<<1, 1024, 0, stream>>>(cnt_i, row_st, cursor, N);
  k_scatter<<<(E2 + 255) / 256, 256, 0, stream>>>(dst, cursor, perm, E, E2);

  // layer 1 projections: xl1=regA, xr1=regB
  dim3 g1((N + 63) / 64, 4);
  k_gemm_nt<<<g1, 256, 0, stream>>>(x, Wl1, bl1, regA, N, 256, F);
  k_gemm_nt<<<g1, 256, 0, stream>>>(x, Wr1, br1, regB, N, 256, F);
  // fused scores+softmax+agg; h1 overwrites xr1 (regB) AFTER reading xr[n] to regs
  // (safe: each wave reads xr row n before writing out row n; different waves
  //  touch different rows)
  k_fused1<<<(N + 3) / 4, 256, 0, stream>>>(regA, regB, src, eattr, mean_ea,
                                            perm, row_st, We1, att1, bias1, regB, E, N);

  // layer 2 projections from h1(regB): xl2 = regA, xr2 = regA + N*64
  float* xl2 = regA;
  float* xr2 = regA + (size_t)N * 64;
  float* h2  = regA + (size_t)N * 128;
  dim3 g2((N + 63) / 64, 1);
  k_gemm_nt<<<g2, 256, 0, stream>>>(regB, Wl2, bl2, xl2, N, 64, 256);
  k_gemm_nt<<<g2, 256, 0, stream>>>(regB, Wr2, br2, xr2, N, 64, 256);
  k_fused2<<<(N + 3) / 4, 256, 0, stream>>>(xl2, xr2, src, eattr, mean_ea,
                                            perm, row_st, We2, att2, bias2, h2, E, N);

  // head
  k_pool<<<128, 256, 0, stream>>>(h2, g_sum, N);
  k_head<<<1, 64, 0, stream>>>(g_sum, Wp, bp, alpha, g, out, N, NA);
  k_aflag<<<1, 128, 0, stream>>>(actions, aflag, n_act);
  int nb = (NA + 255) / 256;
  k_logits<<<nb, 256, 0, stream>>>(g, Wf, bf, aflag, src, dst, logits, gmax_key, E, NA);
  k_exp<<<nb, 256, 0, stream>>>(logits, gmax_key, gsum, NA);
  k_norm<<<nb, 256, 0, stream>>>(logits, gsum, out, NA);
}

// Round 3
// 505.380 us; speedup vs baseline: 1.5934x; 1.2173x over previous
//
#include <hip/hip_runtime.h>
#include <math.h>

typedef __attribute__((ext_vector_type(8))) short short8;
typedef __attribute__((ext_vector_type(4))) float f32x4;

// ---------------- helpers ----------------
__device__ __forceinline__ float wred_sum(float v) {
#pragma unroll
  for (int off = 32; off; off >>= 1) v += __shfl_xor(v, off, 64);
  return v;
}
__device__ __forceinline__ float wred_max(float v) {
#pragma unroll
  for (int off = 32; off; off >>= 1) v = fmaxf(v, __shfl_xor(v, off, 64));
  return v;
}
__device__ __forceinline__ unsigned f2key(float x) {
  unsigned b = __float_as_uint(x);
  return (b & 0x80000000u) ? ~b : (b | 0x80000000u);
}
__device__ __forceinline__ float key2f(unsigned k) {
  unsigned b = (k & 0x80000000u) ? (k & 0x7FFFFFFFu) : ~k;
  return __uint_as_float(b);
}
// bf16 <-> f32
__device__ __forceinline__ float b2f(unsigned short u) {
  return __uint_as_float(((unsigned)u) << 16);
}
__device__ __forceinline__ unsigned short f2b(float f) {
  unsigned b = __float_as_uint(f);
  return (unsigned short)((b + 0x7FFFu + ((b >> 16) & 1u)) >> 16);
}

// ---------------- f32 -> bf16 cast (5 segments, one launch) ----------------
__global__ __launch_bounds__(256) void k_cast5(
    const float* __restrict__ s0, ushort* __restrict__ d0, int n0,
    const float* __restrict__ s1, ushort* __restrict__ d1, int n1,
    const float* __restrict__ s2, ushort* __restrict__ d2, int n2,
    const float* __restrict__ s3, ushort* __restrict__ d3, int n3,
    const float* __restrict__ s4, ushort* __restrict__ d4, int n4) {
  int t = (blockIdx.x * 256 + threadIdx.x) * 4;
  const float* s; ushort* d; int off = t;
  if (off < n0) { s = s0; d = d0; }
  else { off -= n0;
    if (off < n1) { s = s1; d = d1; }
    else { off -= n1;
      if (off < n2) { s = s2; d = d2; }
      else { off -= n2;
        if (off < n3) { s = s3; d = d3; }
        else { off -= n3;
          if (off < n4) { s = s4; d = d4; }
          else return; } } } }
  float4 v = *(const float4*)(s + off);
  ushort4 o;
  o.x = f2b(v.x); o.y = f2b(v.y); o.z = f2b(v.z); o.w = f2b(v.w);
  *(ushort4*)(d + off) = o;
}

// ---------------- self-loop mean edge_attr + degree count ----------------
__global__ __launch_bounds__(256) void k_count_ea(const int* __restrict__ dst,
    const float* __restrict__ ea, int* __restrict__ cnt_i,
    float* __restrict__ sum_ea, int E) {
  int e = blockIdx.x * 256 + threadIdx.x;
  if (e >= E) return;
  int d = dst[e];
  atomicAdd(&cnt_i[d], 1);
  atomicAdd(&sum_ea[d], ea[e]);
}

__global__ __launch_bounds__(256) void k_mean(const int* __restrict__ cnt_i,
    const float* __restrict__ sum_ea, float* __restrict__ mean_ea, int N) {
  int n = blockIdx.x * 256 + threadIdx.x;
  if (n >= N) return;
  mean_ea[n] = sum_ea[n] / fmaxf((float)cnt_i[n], 1.0f);
}

// exclusive scan of (cnt+1) over N nodes -> row_start[N+1], cursor copy
__global__ __launch_bounds__(1024) void k_scan(const int* __restrict__ cnt_i,
    int* __restrict__ row_st, int* __restrict__ cursor, int N) {
  __shared__ int sums[1024];
  int tid = threadIdx.x;
  int per = (N + 1023) / 1024;
  int begin = tid * per, end = min(begin + per, N);
  int s = 0;
  for (int i = begin; i < end; ++i) s += cnt_i[i] + 1;
  sums[tid] = s;
  __syncthreads();
  for (int off = 1; off < 1024; off <<= 1) {
    int v = (tid >= off) ? sums[tid - off] : 0;
    __syncthreads();
    sums[tid] += v;
    __syncthreads();
  }
  int prefix = (tid == 0) ? 0 : sums[tid - 1];
  for (int i = begin; i < end; ++i) {
    row_st[i] = prefix;
    cursor[i] = prefix;
    prefix += cnt_i[i] + 1;
  }
  if (tid == 0) row_st[N] = sums[1023];
}

// scatter edge ids (incl. self loops e=E+n) into CSR perm
__global__ __launch_bounds__(256) void k_scatter(const int* __restrict__ dst,
    int* __restrict__ cursor, int* __restrict__ perm, int E, int E2) {
  int e = blockIdx.x * 256 + threadIdx.x;
  if (e >= E2) return;
  int d = (e < E) ? dst[e] : (e - E);
  int pos = atomicAdd(&cursor[d], 1);
  perm[pos] = e;
}

// ---------------- bf16 MFMA GEMM: C[M,Nc](bf16) = A[M,K](bf16) * W[Nc,K](bf16)^T + bias(f32)
// block = 256 (4 waves); tile 64 rows x 64 cols; wave w -> rows m0+16w.., all 64 cols
__global__ __launch_bounds__(256) void k_gemm_mfma(const ushort* __restrict__ A,
    const ushort* __restrict__ W, const float* __restrict__ bias,
    ushort* __restrict__ C, int M, int Nc, int K) {
  int wave = threadIdx.x >> 6, lane = threadIdx.x & 63;
  int m0 = blockIdx.x * 64 + wave * 16;
  int n0 = blockIdx.y * 64;
  int r = lane & 15, g = lane >> 4;
  f32x4 acc[4] = {};
  int am = min(m0 + r, M - 1);
  const ushort* Arow = A + (size_t)am * K + g * 8;
  const ushort* Wrow = W + (size_t)(n0 + r) * K + g * 8;
  for (int k0 = 0; k0 < K; k0 += 32) {
    short8 a = *(const short8*)(const void*)(Arow + k0);
#pragma unroll
    for (int c = 0; c < 4; ++c) {
      short8 b = *(const short8*)(const void*)(Wrow + (size_t)c * 16 * K + k0);
      acc[c] = __builtin_amdgcn_mfma_f32_16x16x32_bf16(a, b, acc[c], 0, 0, 0);
    }
  }
  // D: col = lane&15 (=r), row = 4*(lane>>4)+j (=4g+j)
#pragma unroll
  for (int c = 0; c < 4; ++c) {
    int gn = n0 + c * 16 + r;
    float bv = bias[gn];
#pragma unroll
    for (int j = 0; j < 4; ++j) {
      int gm = m0 + g * 4 + j;
      if (gm < M) C[(size_t)gm * Nc + gn] = f2b(acc[c][j] + bv);
    }
  }
}

// ---------------- layer 1 fused: scores + online softmax + aggregation ----------------
// one wave per node; lane holds channels 4*lane..4*lane+3 (head = lane>>4)
__global__ __launch_bounds__(256) void k_fused1(const ushort* __restrict__ xl,
    const ushort* __restrict__ xr, const int* __restrict__ src,
    const float* __restrict__ ea, const float* __restrict__ mean_ea,
    const int* __restrict__ perm, const int* __restrict__ row_st,
    const float* __restrict__ We, const float* __restrict__ att,
    const float* __restrict__ bias, ushort* __restrict__ out, int E, int N) {
  int n = blockIdx.x * 4 + (threadIdx.x >> 6);
  int lane = threadIdx.x & 63;
  if (n >= N) return;
  const float4 We4 = ((const float4*)We)[lane];
  const float4 at4 = ((const float4*)att)[lane];
  ushort4 xru = *(const ushort4*)(xr + (size_t)n * 256 + lane * 4);
  float xrx = b2f(xru.x), xry = b2f(xru.y), xrz = b2f(xru.z), xrw = b2f(xru.w);
  int a = row_st[n], b = row_st[n + 1];
  float m = -INFINITY, den = 0.f;
  float ax = 0.f, ay = 0.f, az = 0.f, aw = 0.f;
  int e0 = perm[a];
  int sn_nx = (e0 < E) ? src[e0] : n;
  float av_nx = (e0 < E) ? ea[e0] : mean_ea[n];
  for (int i = a; i < b; ++i) {
    int sn = sn_nx;
    float av = av_nx;
    ushort4 xu = *(const ushort4*)(xl + (size_t)sn * 256 + lane * 4);
    if (i + 1 < b) {
      int e2 = perm[i + 1];
      sn_nx = (e2 < E) ? src[e2] : n;
      av_nx = (e2 < E) ? ea[e2] : mean_ea[n];
    }
    float x0 = b2f(xu.x), x1 = b2f(xu.y), x2 = b2f(xu.z), x3 = b2f(xu.w);
    float vx = x0 + xrx + av * We4.x; vx = vx > 0.f ? vx : 0.2f * vx;
    float vy = x1 + xry + av * We4.y; vy = vy > 0.f ? vy : 0.2f * vy;
    float vz = x2 + xrz + av * We4.z; vz = vz > 0.f ? vz : 0.2f * vz;
    float vw = x3 + xrw + av * We4.w; vw = vw > 0.f ? vw : 0.2f * vw;
    float t = at4.x * vx + at4.y * vy + at4.z * vz + at4.w * vw;
    // reduce within 16-lane head group
    t += __shfl_xor(t, 1, 16);
    t += __shfl_xor(t, 2, 16);
    t += __shfl_xor(t, 4, 16);
    t += __shfl_xor(t, 8, 16);
    if (t > m) {
      float sc = __expf(m - t);
      m = t;
      den *= sc; ax *= sc; ay *= sc; az *= sc; aw *= sc;
    }
    float ex = __expf(t - m);
    den += ex;
    ax += ex * x0; ay += ex * x1; az += ex * x2; aw += ex * x3;
  }
  float inv = 1.f / (den + 1e-16f);
  const float4 b4 = ((const float4*)bias)[lane];
  ushort4 o;
  o.x = f2b(fmaxf(ax * inv + b4.x, 0.f));
  o.y = f2b(fmaxf(ay * inv + b4.y, 0.f));
  o.z = f2b(fmaxf(az * inv + b4.z, 0.f));
  o.w = f2b(fmaxf(aw * inv + b4.w, 0.f));
  *(ushort4*)(out + (size_t)n * 256 + lane * 4) = o;
}

// ---------------- layer 2 fused (H=1, C=64) ----------------
__global__ __launch_bounds__(256) void k_fused2(const ushort* __restrict__ xl,
    const ushort* __restrict__ xr, const int* __restrict__ src,
    const float* __restrict__ ea, const float* __restrict__ mean_ea,
    const int* __restrict__ perm, const int* __restrict__ row_st,
    const float* __restrict__ We, const float* __restrict__ att,
    const float* __restrict__ bias, float* __restrict__ out, int E, int N) {
  int n = blockIdx.x * 4 + (threadIdx.x >> 6);
  int lane = threadIdx.x & 63;
  if (n >= N) return;
  const float Wev = We[lane];
  const float atv = att[lane];
  const float xrv = b2f(xr[(size_t)n * 64 + lane]);
  int a = row_st[n], b = row_st[n + 1];
  float m = -INFINITY, den = 0.f, acc = 0.f;
  int e0 = perm[a];
  int sn_nx = (e0 < E) ? src[e0] : n;
  float av_nx = (e0 < E) ? ea[e0] : mean_ea[n];
  for (int i = a; i < b; ++i) {
    int sn = sn_nx;
    float av = av_nx;
    float xv = b2f(xl[(size_t)sn * 64 + lane]);
    if (i + 1 < b) {
      int e2 = perm[i + 1];
      sn_nx = (e2 < E) ? src[e2] : n;
      av_nx = (e2 < E) ? ea[e2] : mean_ea[n];
    }
    float v = xv + xrv + av * Wev;
    v = v > 0.f ? v : 0.2f * v;
    float t = wred_sum(atv * v);
    if (t > m) {
      float sc = __expf(m - t);
      m = t; den *= sc; acc *= sc;
    }
    float ex = __expf(t - m);
    den += ex;
    acc += ex * xv;
  }
  float v = acc / (den + 1e-16f) + bias[lane];
  out[(size_t)n * 64 + lane] = v > 0.f ? v : 0.f;
}

// ---------------- global mean pool ----------------
__global__ __launch_bounds__(256) void k_pool(const float* __restrict__ h2,
    float* __restrict__ g_sum, int N) {
  __shared__ float red[4][64];
  int b = blockIdx.x, tid = threadIdx.x;
  int lane = tid & 63, w = tid >> 6;
  int rows_per = (N + gridDim.x - 1) / gridDim.x;
  int r0 = b * rows_per, r1 = min(r0 + rows_per, N);
  float s = 0;
  for (int r = r0 + w; r < r1; r += 4) s += h2[(size_t)r * 64 + lane];
  red[w][lane] = s;
  __syncthreads();
  if (w == 0) {
    float v = red[0][lane] + red[1][lane] + red[2][lane] + red[3][lane];
    atomicAdd(&g_sum[lane], v);
  }
}

// mean -> g, state potential, sigmoid(alpha)
__global__ void k_head(const float* __restrict__ g_sum, const float* __restrict__ Wp,
    const float* __restrict__ bp, const float* __restrict__ alpha,
    float* __restrict__ g, float* __restrict__ out, int N, int NA) {
  int lane = threadIdx.x;
  float gv = g_sum[lane] / (float)N;
  g[lane] = gv;
  float t = wred_sum(gv * Wp[lane]);
  if (lane == 0) {
    float sp = t + bp[0];
    out[NA] = sp > 0.f ? sp : 0.f;
    out[NA + 1] = 1.f / (1.f + __expf(-alpha[0]));
  }
}

__global__ void k_aflag(const int* __restrict__ actions, unsigned char* __restrict__ aflag,
                        int n_act) {
  int i = threadIdx.x;
  if (i < n_act) aflag[actions[i]] = 1;
}

// ---------------- masked logits + softmax (3 passes) ----------------
__global__ __launch_bounds__(256) void k_logits(const float* __restrict__ g,
    const float* __restrict__ Wf, const float* __restrict__ bf,
    const unsigned char* __restrict__ aflag, const int* __restrict__ src,
    const int* __restrict__ dst, float* __restrict__ logits,
    unsigned* __restrict__ gmax_key, int E, int NA) {
  __shared__ float gs[64];
  int tid = threadIdx.x;
  if (tid < 64) gs[tid] = g[tid];
  __syncthreads();
  int i = blockIdx.x * 256 + tid;
  float val = -INFINITY;
  if (i < NA) {
    bool keep = (!aflag[i]) && (i >= E || src[i] != dst[i]);
    if (keep) {
      const float4* w4 = (const float4*)(Wf + (size_t)i * 64);
      float acc = 0.f;
#pragma unroll
      for (int j = 0; j < 16; ++j) {
        float4 w = w4[j];
        acc += w.x * gs[4 * j] + w.y * gs[4 * j + 1] + w.z * gs[4 * j + 2] + w.w * gs[4 * j + 3];
      }
      val = acc + bf[i];
    }
    logits[i] = val;
  }
  float mv = wred_max(val);
  if ((tid & 63) == 0) atomicMax(gmax_key, f2key(mv));
}

__global__ __launch_bounds__(256) void k_exp(float* __restrict__ logits,
    const unsigned* __restrict__ gmax_key, float* __restrict__ gsum, int NA) {
  int i = blockIdx.x * 256 + threadIdx.x;
  float gmax = key2f(*gmax_key);
  float ex = 0.f;
  if (i < NA) {
    float v = logits[i];
    ex = (v == -INFINITY) ? 0.f : __expf(v - gmax);
    logits[i] = ex;
  }
  float s = wred_sum(ex);
  if ((threadIdx.x & 63) == 0) atomicAdd(gsum, s);
}

__global__ __launch_bounds__(256) void k_norm(const float* __restrict__ logits,
    const float* __restrict__ gsum, float* __restrict__ out, int NA) {
  int i = blockIdx.x * 256 + threadIdx.x;
  if (i < NA) out[i] = logits[i] / (*gsum);
}

// ---------------- launch ----------------
extern "C" void kernel_launch(void* const* d_in, const int* in_sizes, int n_in,
                              void* d_out, int out_size, void* d_ws, size_t ws_size,
                              hipStream_t stream) {
  const float* x      = (const float*)d_in[0];
  const int*   eidx   = (const int*)d_in[1];
  const float* eattr  = (const float*)d_in[2];
  const int*   actions= (const int*)d_in[3];
  const float* Wl1 = (const float*)d_in[4];
  const float* bl1 = (const float*)d_in[5];
  const float* Wr1 = (const float*)d_in[6];
  const float* br1 = (const float*)d_in[7];
  const float* We1 = (const float*)d_in[8];
  const float* att1= (const float*)d_in[9];
  const float* bias1=(const float*)d_in[10];
  const float* Wl2 = (const float*)d_in[11];
  const float* bl2 = (const float*)d_in[12];
  const float* Wr2 = (const float*)d_in[13];
  const float* br2 = (const float*)d_in[14];
  const float* We2 = (const float*)d_in[15];
  const float* att2= (const float*)d_in[16];
  const float* bias2=(const float*)d_in[17];
  const float* Wf  = (const float*)d_in[18];
  const float* bf  = (const float*)d_in[19];
  const float* Wp  = (const float*)d_in[20];
  const float* bp  = (const float*)d_in[21];
  const float* alpha=(const float*)d_in[22];

  const int F = 128;
  const int N = in_sizes[0] / F;       // 20000
  const int E = in_sizes[2];           // 400000
  const int E2 = E + N;
  const int NA = E + 1;
  const int n_act = in_sizes[3];
  const int* src = eidx;
  const int* dst = eidx + E;
  const int hid = 64, H = 4;

  float* ws = (float*)d_ws;
  size_t p = 0;
  int*      cnt_i    = (int*)(ws + p);      p += (size_t)N;
  float*    sum_ea   = ws + p;              p += (size_t)N;
  float*    g_sum    = ws + p;              p += 64;
  unsigned* gmax_key = (unsigned*)(ws + p); p += 64;
  float*    gsum     = ws + p;              p += 64;
  size_t zero_bytes = p * sizeof(float);
  float*    g        = ws + p;              p += 64;
  float*    mean_ea  = ws + p;              p += (size_t)N;
  int*      row_st   = (int*)(ws + p);      p += (size_t)N + 64;
  int*      cursor   = (int*)(ws + p);      p += (size_t)N;
  int*      perm     = (int*)(ws + p);      p += (size_t)E2;
  float*    logits   = ws + p;              p += (size_t)NA + 64;
  p = (p + 3) & ~(size_t)3;                 // 16B align for bf16 region
  float*    h2       = ws + p;              p += (size_t)N * hid;
  ushort* ub = (ushort*)(ws + p);
  size_t q = 0;
  ushort* xb   = ub + q; q += (size_t)N * F;        // x bf16
  ushort* wl1b = ub + q; q += (size_t)256 * 128;
  ushort* wr1b = ub + q; q += (size_t)256 * 128;
  ushort* wl2b = ub + q; q += (size_t)64 * 256;
  ushort* wr2b = ub + q; q += (size_t)64 * 256;
  ushort* xl1b = ub + q; q += (size_t)N * 256;
  ushort* xr1b = ub + q; q += (size_t)N * 256;
  ushort* h1b  = ub + q; q += (size_t)N * 256;
  ushort* xl2b = ub + q; q += (size_t)N * 64;
  ushort* xr2b = ub + q; q += (size_t)N * 64;
  unsigned char* aflag = (unsigned char*)(ub + q);

  float* out = (float*)d_out;

  hipMemsetAsync(d_ws, 0, zero_bytes, stream);
  hipMemsetAsync(aflag, 0, (size_t)NA, stream);

  // casts: x + 4 weight matrices -> bf16
  {
    int n0 = N * F, n1 = 256 * 128, n2 = 256 * 128, n3 = 64 * 256, n4 = 64 * 256;
    int tot4 = (n0 + n1 + n2 + n3 + n4) / 4;
    k_cast5<<<(tot4 + 255) / 256, 256, 0, stream>>>(
        x, xb, n0, Wl1, wl1b, n1, Wr1, wr1b, n2, Wl2, wl2b, n3, Wr2, wr2b, n4);
  }

  // CSR build + self-loop edge attr
  k_count_ea<<<(E + 255) / 256, 256, 0, stream>>>(dst, eattr, cnt_i, sum_ea, E);
  k_mean<<<(N + 255) / 256, 256, 0, stream>>>(cnt_i, sum_ea, mean_ea, N);
  k_scan<<<1, 1024, 0, stream>>>(cnt_i, row_st, cursor, N);
  k_scatter<<<(E2 + 255) / 256, 256, 0, stream>>>(dst, cursor, perm, E, E2);

  // layer 1 projections (bf16 MFMA): xl1b, xr1b
  {
    dim3 g1((N + 63) / 64, 256 / 64);
    k_gemm_mfma<<<g1, 256, 0, stream>>>(xb, wl1b, bl1, xl1b, N, 256, 128);
    k_gemm_mfma<<<g1, 256, 0, stream>>>(xb, wr1b, br1, xr1b, N, 256, 128);
  }
  k_fused1<<<(N + 3) / 4, 256, 0, stream>>>(xl1b, xr1b, src, eattr, mean_ea,
                                            perm, row_st, We1, att1, bias1, h1b, E, N);

  // layer 2 projections from h1b: xl2b, xr2b
  {
    dim3 g2((N + 63) / 64, 1);
    k_gemm_mfma<<<g2, 256, 0, stream>>>(h1b, wl2b, bl2, xl2b, N, 64, 256);
    k_gemm_mfma<<<g2, 256, 0, stream>>>(h1b, wr2b, br2, xr2b, N, 64, 256);
  }
  k_fused2<<<(N + 3) / 4, 256, 0, stream>>>(xl2b, xr2b, src, eattr, mean_ea,
                                            perm, row_st, We2, att2, bias2, h2, E, N);

  // head
  k_pool<<<128, 256, 0, stream>>>(h2, g_sum, N);
  k_head<<<1, 64, 0, stream>>>(g_sum, Wp, bp, alpha, g, out, N, NA);
  k_aflag<<<1, 128, 0, stream>>>(actions, aflag, n_act);
  int nb = (NA + 255) / 256;
  k_logits<<<nb, 256, 0, stream>>>(g, Wf, bf, aflag, src, dst, logits, gmax_key, E, NA);
  k_exp<<<nb, 256, 0, stream>>>(logits, gmax_key, gsum, NA);
  k_norm<<<nb, 256, 0, stream>>>(logits, gsum, out, NA);
}